// Round 1
// baseline (342.882 us; speedup 1.0000x reference)
//
#include <hip/hip_runtime.h>

#define OBS_DIM 64
#define ACT_DIM 12
#define IN_DIM  76
#define HID     256
#define BATCH   1024
#define CAP     100000
#define NKT     64
#define NCHUNK  ((CAP + NKT - 1) / NKT)      /* 1563 */
#define CGRP    16
#define CPG     ((NCHUNK + CGRP - 1) / CGRP) /* 98 */
#define LOG2E   1.4426950408889634f

typedef __attribute__((ext_vector_type(8))) _Float16 f16x8;
typedef __attribute__((ext_vector_type(4))) _Float16 f16x4;
typedef __attribute__((ext_vector_type(4))) float    f32x4;

// ---------------- trunk: x@W + b, LayerNorm, tanh -> A (fp16) ----------------
__global__ __launch_bounds__(256) void np_trunk(const float* __restrict__ obs,
                                                const float* __restrict__ act,
                                                const float* __restrict__ W,
                                                const float* __restrict__ bias,
                                                const float* __restrict__ gamma,
                                                const float* __restrict__ beta,
                                                _Float16* __restrict__ A) {
    const int row = blockIdx.x;
    const int t = threadIdx.x;
    __shared__ float x[80];
    __shared__ float red[8];
    if (t < OBS_DIM) x[t] = obs[row * OBS_DIM + t];
    else if (t < IN_DIM) x[t] = act[row * ACT_DIM + (t - OBS_DIM)];
    __syncthreads();
    float h = bias[t];
#pragma unroll
    for (int k = 0; k < IN_DIM; ++k) h = fmaf(x[k], W[k * HID + t], h);
    // block reduce sum(h), sum(h^2)
    float s1 = h, s2 = h * h;
#pragma unroll
    for (int m = 1; m < 64; m <<= 1) { s1 += __shfl_xor(s1, m, 64); s2 += __shfl_xor(s2, m, 64); }
    const int wave = t >> 6;
    if ((t & 63) == 0) { red[wave] = s1; red[4 + wave] = s2; }
    __syncthreads();
    const float S1 = red[0] + red[1] + red[2] + red[3];
    const float S2 = red[4] + red[5] + red[6] + red[7];
    const float mu = S1 * (1.0f / 256.0f);
    const float var = S2 * (1.0f / 256.0f) - mu * mu;
    const float rs = rsqrtf(var + 1e-5f);
    const float g = (h - mu) * rs * gamma[t] + beta[t];
    // tanh(g) = 1 - 2/(exp2(2g*log2e)+1)  (safe at +/-inf of the exp)
    const float e = exp2f(g * (2.0f * LOG2E));
    const float ph = 1.0f - 2.0f / (e + 1.0f);
    A[row * HID + t] = (_Float16)ph;
}

// ------------- key-stationary fused GEMM + per-64-key-tile softmax -------------
// grid = NCHUNK blocks; block owns keys [chunk*64, chunk*64+64), loops 8 rowgroups
__global__ __launch_bounds__(256, 2) void np_gemm(const float* __restrict__ keys,
                                                  const float* __restrict__ vals,
                                                  const _Float16* __restrict__ A,
                                                  float* __restrict__ pm,
                                                  float* __restrict__ pl,
                                                  float* __restrict__ pa) {
    const int chunk = blockIdx.x;
    const int kb = chunk * NKT;
    const int t = threadIdx.x;
    const int lane = t & 63;
    const int wave = t >> 6;
    const int q = lane >> 4;      // quad within wave
    const int kcol = lane & 15;   // col (key) within 16-tile

    __shared__ __align__(16) _Float16 Bt[8][4][64][8]; // [kstep][quad][key][8 halfs] = 32 KB
    __shared__ float nred[256];
    __shared__ float n2[64];
    __shared__ float vv[64];

    // ---- stage keys fp32 -> fp16 LDS (MFMA-frag layout) + fp32 sq-sums ----
    {
        const int keyl = t >> 2;
        const int key = kb + keyl;
        const int k0 = (t & 3) * 64;
        const bool ok = key < CAP;
        const float* src = keys + (size_t)key * HID + k0;
        float sq = 0.f;
#pragma unroll
        for (int i = 0; i < 16; ++i) {
            float4 f = make_float4(0.f, 0.f, 0.f, 0.f);
            if (ok) f = ((const float4*)src)[i];
            sq = fmaf(f.x, f.x, sq); sq = fmaf(f.y, f.y, sq);
            sq = fmaf(f.z, f.z, sq); sq = fmaf(f.w, f.w, sq);
            const int k = k0 + i * 4;
            f16x4 hv = {(_Float16)f.x, (_Float16)f.y, (_Float16)f.z, (_Float16)f.w};
            *(f16x4*)(&Bt[k >> 5][(k >> 3) & 3][keyl][k & 7]) = hv;
        }
        nred[t] = sq;
        if (t < NKT) {
            float v = 0.f;
            if (kb + t < CAP) v = vals[kb + t];
            vv[t] = v;
        }
    }
    __syncthreads();
    if (t < NKT) {
        const float n = nred[4 * t] + nred[4 * t + 1] + nred[4 * t + 2] + nred[4 * t + 3];
        n2[t] = (kb + t < CAP) ? n * LOG2E : 3e38f;  // pad keys -> logit -inf
    }
    __syncthreads();

    float nn[4], vvl[4];
#pragma unroll
    for (int c = 0; c < 4; ++c) { nn[c] = n2[c * 16 + kcol]; vvl[c] = vv[c * 16 + kcol]; }
    const float C1 = 2.0f * LOG2E;

#pragma unroll 1
    for (int rg = 0; rg < 8; ++rg) {
        const int rowbase = rg * 128 + wave * 32;
        // A fragments: 2 bands x 8 ksteps, held in registers
        f16x8 af[2][8];
#pragma unroll
        for (int tb = 0; tb < 2; ++tb) {
            const f16x8* ap = (const f16x8*)(A + (size_t)(rowbase + tb * 16 + kcol) * HID + q * 8);
#pragma unroll
            for (int s = 0; s < 8; ++s) af[tb][s] = ap[s * 4];
        }
        f32x4 acc[2][4];
#pragma unroll
        for (int tb = 0; tb < 2; ++tb)
#pragma unroll
            for (int c = 0; c < 4; ++c) acc[tb][c] = (f32x4){0.f, 0.f, 0.f, 0.f};

#pragma unroll
        for (int s = 0; s < 8; ++s) {
#pragma unroll
            for (int c = 0; c < 4; ++c) {
                f16x8 bf = *(const f16x8*)(&Bt[s][q][c * 16 + kcol][0]);
                acc[0][c] = __builtin_amdgcn_mfma_f32_16x16x32_f16(af[0][s], bf, acc[0][c], 0, 0, 0);
                acc[1][c] = __builtin_amdgcn_mfma_f32_16x16x32_f16(af[1][s], bf, acc[1][c], 0, 0, 0);
            }
        }

        // ---- one-shot softmax partials over this 64-key tile ----
#pragma unroll
        for (int tb = 0; tb < 2; ++tb) {
#pragma unroll
            for (int r = 0; r < 4; ++r) {
                float L0 = fmaf(acc[tb][0][r], C1, -nn[0]);
                float L1 = fmaf(acc[tb][1][r], C1, -nn[1]);
                float L2 = fmaf(acc[tb][2][r], C1, -nn[2]);
                float L3 = fmaf(acc[tb][3][r], C1, -nn[3]);
                float m = fmaxf(fmaxf(L0, L1), fmaxf(L2, L3));
#pragma unroll
                for (int sh = 1; sh < 16; sh <<= 1) m = fmaxf(m, __shfl_xor(m, sh, 16));
                const float w0 = exp2f(L0 - m);
                const float w1 = exp2f(L1 - m);
                const float w2 = exp2f(L2 - m);
                const float w3 = exp2f(L3 - m);
                float lsum = (w0 + w1) + (w2 + w3);
                float asum = fmaf(w0, vvl[0], fmaf(w1, vvl[1], fmaf(w2, vvl[2], w3 * vvl[3])));
#pragma unroll
                for (int sh = 1; sh < 16; sh <<= 1) {
                    lsum += __shfl_xor(lsum, sh, 16);
                    asum += __shfl_xor(asum, sh, 16);
                }
                if (kcol == 0) {
                    const int row = rowbase + tb * 16 + q * 4 + r;
                    const size_t idx = (size_t)chunk * BATCH + row;
                    pm[idx] = m; pl[idx] = lsum; pa[idx] = asum;
                }
            }
        }
    }
}

// ------------- merge stage 1: 16 chunk-groups x 16 row-blocks -------------
__global__ __launch_bounds__(256) void np_merge1(const float* __restrict__ pm,
                                                 const float* __restrict__ pl,
                                                 const float* __restrict__ pa,
                                                 float* __restrict__ pm2,
                                                 float* __restrict__ pl2,
                                                 float* __restrict__ pa2) {
    const int rb = blockIdx.x & 15;
    const int cgB = blockIdx.x >> 4;
    const int t = threadIdx.x;
    const int row = rb * 64 + (t & 63);
    const int cg = t >> 6;
    const int cend = min((cgB + 1) * CPG, NCHUNK);
    float M = -3e38f, L = 0.f, Acc = 0.f;
    for (int c = cgB * CPG + cg; c < cend; c += 4) {
        const size_t idx = (size_t)c * BATCH + row;
        const float m = pm[idx], l = pl[idx], a = pa[idx];
        const float Mn = fmaxf(M, m);
        const float s0 = exp2f(M - Mn);
        const float s1 = exp2f(m - Mn);
        L = fmaf(L, s0, l * s1);
        Acc = fmaf(Acc, s0, a * s1);
        M = Mn;
    }
    __shared__ float sm[256], sl[256], sa[256];
    sm[t] = M; sl[t] = L; sa[t] = Acc;
    __syncthreads();
    if (t < 64) {
        const float M0 = sm[t], M1 = sm[t + 64], M2 = sm[t + 128], M3 = sm[t + 192];
        const float Mf = fmaxf(fmaxf(M0, M1), fmaxf(M2, M3));
        const float e0 = exp2f(M0 - Mf), e1 = exp2f(M1 - Mf), e2 = exp2f(M2 - Mf), e3 = exp2f(M3 - Mf);
        const float Lf = sl[t] * e0 + sl[t + 64] * e1 + sl[t + 128] * e2 + sl[t + 192] * e3;
        const float Af = sa[t] * e0 + sa[t + 64] * e1 + sa[t + 128] * e2 + sa[t + 192] * e3;
        const size_t o = (size_t)cgB * BATCH + rb * 64 + t;
        pm2[o] = Mf; pl2[o] = Lf; pa2[o] = Af;
    }
}

// ------------- merge stage 2: final 16-way merge, write q1==q2 -------------
__global__ __launch_bounds__(256) void np_merge2(const float* __restrict__ pm2,
                                                 const float* __restrict__ pl2,
                                                 const float* __restrict__ pa2,
                                                 float* __restrict__ out) {
    const int row = blockIdx.x * 256 + threadIdx.x;
    float M = -3e38f, L = 0.f, Acc = 0.f;
#pragma unroll 1
    for (int g = 0; g < CGRP; ++g) {
        const size_t idx = (size_t)g * BATCH + row;
        const float m = pm2[idx], l = pl2[idx], a = pa2[idx];
        const float Mn = fmaxf(M, m);
        const float s0 = exp2f(M - Mn);
        const float s1 = exp2f(m - Mn);
        L = fmaf(L, s0, l * s1);
        Acc = fmaf(Acc, s0, a * s1);
        M = Mn;
    }
    const float qv = Acc / L;
    out[row] = qv;
    out[BATCH + row] = qv;
}

extern "C" void kernel_launch(void* const* d_in, const int* in_sizes, int n_in,
                              void* d_out, int out_size, void* d_ws, size_t ws_size,
                              hipStream_t stream) {
    const float* obs   = (const float*)d_in[0];
    const float* act   = (const float*)d_in[1];
    const float* W     = (const float*)d_in[2];
    const float* bias  = (const float*)d_in[3];
    const float* gamma = (const float*)d_in[4];
    const float* beta  = (const float*)d_in[5];
    const float* keys  = (const float*)d_in[6];
    const float* vals  = (const float*)d_in[7];
    float* out = (float*)d_out;

    char* w = (char*)d_ws;
    _Float16* A = (_Float16*)w;                       // 1024*256*2 = 512 KB
    float* pm = (float*)(w + (1 << 19));
    float* pl = pm + (size_t)NCHUNK * BATCH;          // 3 x 6.25 MB
    float* pa = pl + (size_t)NCHUNK * BATCH;
    float* pm2 = pa + (size_t)NCHUNK * BATCH;         // 3 x 64 KB
    float* pl2 = pm2 + (size_t)CGRP * BATCH;
    float* pa2 = pl2 + (size_t)CGRP * BATCH;

    np_trunk<<<BATCH, 256, 0, stream>>>(obs, act, W, bias, gamma, beta, A);
    np_gemm<<<NCHUNK, 256, 0, stream>>>(keys, vals, A, pm, pl, pa);
    np_merge1<<<CGRP * 16, 256, 0, stream>>>(pm, pl, pa, pm2, pl2, pa2);
    np_merge2<<<BATCH / 256, 256, 0, stream>>>(pm2, pl2, pa2, out);
}